// Round 1
// baseline (1966.547 us; speedup 1.0000x reference)
//
#include <hip/hip_runtime.h>
#include <hip/hip_bf16.h>

#define HID 64

// ---------------------------------------------------------------------------
// K1: histogram — per edge: deg_w[dst] += ew ; cnt[dst] += 1
// ---------------------------------------------------------------------------
__global__ __launch_bounds__(256) void k_hist(const int* __restrict__ dst,
                                              const float* __restrict__ ew,
                                              float* __restrict__ deg,
                                              int* __restrict__ cnt, int nE) {
    int i = blockIdx.x * blockDim.x + threadIdx.x;
    int stride = gridDim.x * blockDim.x;
    for (; i < nE; i += stride) {
        int d = dst[i];
        atomicAdd(&deg[d], ew[i]);
        atomicAdd(&cnt[d], 1);
    }
}

// ---------------------------------------------------------------------------
// K2: dinv — deg -> rsqrt(deg + 1) in place (self-loop adds 1; deg >= 1 so no clamp issue)
// ---------------------------------------------------------------------------
__global__ __launch_bounds__(256) void k_dinv(float* __restrict__ deg, int n) {
    int i = blockIdx.x * blockDim.x + threadIdx.x;
    if (i < n) {
        float d = deg[i] + 1.0f;
        deg[i] = rsqrtf(fmaxf(d, 1e-12f));
    }
}

// ---------------------------------------------------------------------------
// K3: single-block exclusive scan of cnt -> row_start[0..n], also copied to cursor
//     1024 threads, 4 elems/thread/chunk, wave-scan + cross-wave via LDS
// ---------------------------------------------------------------------------
__global__ __launch_bounds__(1024) void k_scan(const int* __restrict__ cnt,
                                               int* __restrict__ row_start,
                                               int* __restrict__ cursor, int n) {
    __shared__ int wsum[16];
    __shared__ int woff[16];
    __shared__ int carry_s;
    int tid = threadIdx.x;
    int lane = tid & 63, wv = tid >> 6;
    if (tid == 0) carry_s = 0;
    __syncthreads();
    const int CHUNK = 4096;
    for (int base = 0; base < n; base += CHUNK) {
        int idx0 = base + tid * 4;
        int v[4], local = 0;
#pragma unroll
        for (int j = 0; j < 4; ++j) {
            int i = idx0 + j;
            v[j] = (i < n) ? cnt[i] : 0;
            local += v[j];
        }
        // wave-inclusive scan of `local`
        int sc = local;
#pragma unroll
        for (int off = 1; off < 64; off <<= 1) {
            int t = __shfl_up(sc, off);
            if (lane >= off) sc += t;
        }
        if (lane == 63) wsum[wv] = sc;
        __syncthreads();
        if (tid == 0) {
            int acc = 0;
#pragma unroll
            for (int w = 0; w < 16; ++w) { woff[w] = acc; acc += wsum[w]; }
            wsum[0] = acc;  // chunk total
        }
        __syncthreads();
        int excl = carry_s + woff[wv] + sc - local;
#pragma unroll
        for (int j = 0; j < 4; ++j) {
            int i = idx0 + j;
            if (i < n) { row_start[i] = excl; cursor[i] = excl; }
            excl += v[j];
        }
        int total = wsum[0];
        __syncthreads();
        if (tid == 0) carry_s += total;
        __syncthreads();
    }
    if (tid == 0) row_start[n] = carry_s;
}

// ---------------------------------------------------------------------------
// K4: scatter edges into CSR, with precomputed normalized weight
//     w = dinv[src] * ew * dinv[dst]   (reused by all 3 layers)
// ---------------------------------------------------------------------------
__global__ __launch_bounds__(256) void k_scatter(const int* __restrict__ src,
                                                 const int* __restrict__ dst,
                                                 const float* __restrict__ ew,
                                                 const float* __restrict__ dinv,
                                                 int* __restrict__ cursor,
                                                 int* __restrict__ csr_src,
                                                 float* __restrict__ csr_w, int nE) {
    int i = blockIdx.x * blockDim.x + threadIdx.x;
    int stride = gridDim.x * blockDim.x;
    for (; i < nE; i += stride) {
        int s = src[i], d = dst[i];
        float w = dinv[s] * ew[i] * dinv[d];
        int pos = atomicAdd(&cursor[d], 1);
        csr_src[pos] = s;
        csr_w[pos] = w;
    }
}

// ---------------------------------------------------------------------------
// K5: matmul  out[n][f] = sum_k act(in[n][k]) * W[k][f]     (f = lane, wave per node)
//     W staged in LDS; input row loaded coalesced into lane regs, broadcast via shfl
// ---------------------------------------------------------------------------
template <int K, bool SIG>
__global__ __launch_bounds__(256) void k_mm(const float* __restrict__ in,
                                            const float* __restrict__ W,
                                            float* __restrict__ out, int n_nodes) {
    __shared__ float Ws[K * HID];
    for (int i = threadIdx.x; i < K * HID; i += blockDim.x) Ws[i] = W[i];
    __syncthreads();
    int lane = threadIdx.x & 63;
    int wid = threadIdx.x >> 6;
    int wavesTotal = gridDim.x * (blockDim.x >> 6);
    for (int node = blockIdx.x * (blockDim.x >> 6) + wid; node < n_nodes;
         node += wavesTotal) {
        float xr = 0.0f;
        if (lane < K) {
            xr = in[node * K + lane];
            if (SIG) xr = 1.0f / (1.0f + __expf(-xr));
        }
        float acc = 0.0f;
#pragma unroll
        for (int k = 0; k < K; ++k) {
            float xv = __shfl(xr, k);            // wave-uniform broadcast
            acc = fmaf(xv, Ws[k * HID + lane], acc);
        }
        out[node * HID + lane] = acc;
    }
}

// ---------------------------------------------------------------------------
// K6: aggregation — wave per node, lane = feature.
//     acc = b[f] + h[n][f]*dinv[n]^2 + sum_{e in CSR row n} h[src_e][f]*w_e
//     Edge list read coalesced in chunks of 64; src/w broadcast via shfl;
//     manual 4x unroll for memory-level parallelism of the gathers.
// ---------------------------------------------------------------------------
__global__ __launch_bounds__(256) void k_agg(const float* __restrict__ h,
                                             const float* __restrict__ bias,
                                             const float* __restrict__ dinv,
                                             const int* __restrict__ row_start,
                                             const int* __restrict__ csr_src,
                                             const float* __restrict__ csr_w,
                                             float* __restrict__ out, int n_nodes) {
    int lane = threadIdx.x & 63;
    int wid = threadIdx.x >> 6;
    int node = blockIdx.x * 4 + wid;
    if (node >= n_nodes) return;
    float di = dinv[node];
    float acc = bias[lane] + h[node * HID + lane] * di * di;
    int e0 = row_start[node], e1 = row_start[node + 1];
    for (int base = e0; base < e1; base += 64) {
        int m = min(64, e1 - base);
        int s = 0;
        float w = 0.0f;
        if (lane < m) {
            s = csr_src[base + lane];
            w = csr_w[base + lane];
        }
        int j = 0;
        for (; j + 4 <= m; j += 4) {
            int s0 = __shfl(s, j), s1 = __shfl(s, j + 1);
            int s2 = __shfl(s, j + 2), s3 = __shfl(s, j + 3);
            float w0 = __shfl(w, j), w1 = __shfl(w, j + 1);
            float w2 = __shfl(w, j + 2), w3 = __shfl(w, j + 3);
            float h0 = h[s0 * HID + lane];
            float h1 = h[s1 * HID + lane];
            float h2 = h[s2 * HID + lane];
            float h3 = h[s3 * HID + lane];
            acc = fmaf(h0, w0, acc);
            acc = fmaf(h1, w1, acc);
            acc = fmaf(h2, w2, acc);
            acc = fmaf(h3, w3, acc);
        }
        for (; j < m; ++j) {
            int sj = __shfl(s, j);
            float wj = __shfl(w, j);
            acc = fmaf(h[sj * HID + lane], wj, acc);
        }
    }
    out[node * HID + lane] = acc;
}

// ---------------------------------------------------------------------------
// K7: pooling head — p = dot(h3[n], Wout); wave-reduce; atomicAdd per node into
//     psum[batch[n]] and pcnt[batch[n]]. (pooled@Wout == segsum(h3@Wout)/counts)
// ---------------------------------------------------------------------------
__global__ __launch_bounds__(256) void k_pool(const float* __restrict__ h,
                                              const int* __restrict__ batch,
                                              const float* __restrict__ Wout,
                                              float* __restrict__ psum,
                                              float* __restrict__ pcnt, int n_nodes) {
    int lane = threadIdx.x & 63;
    int wid = threadIdx.x >> 6;
    int node = blockIdx.x * 4 + wid;
    if (node >= n_nodes) return;
    float v = h[node * HID + lane] * Wout[lane];
#pragma unroll
    for (int off = 32; off; off >>= 1) v += __shfl_xor(v, off);
    if (lane == 0) {
        int g = batch[node];
        atomicAdd(&psum[g], v);
        atomicAdd(&pcnt[g], 1.0f);
    }
}

// K8: final — out[g] = psum[g]/max(pcnt[g],1) + bout
__global__ __launch_bounds__(64) void k_out(const float* __restrict__ psum,
                                            const float* __restrict__ pcnt,
                                            const float* __restrict__ bout,
                                            float* __restrict__ out, int G) {
    int g = threadIdx.x;
    if (g < G) out[g] = psum[g] / fmaxf(pcnt[g], 1.0f) + bout[0];
}

extern "C" void kernel_launch(void* const* d_in, const int* in_sizes, int n_in,
                              void* d_out, int out_size, void* d_ws, size_t ws_size,
                              hipStream_t stream) {
    const float* x    = (const float*)d_in[0];   // [N,16]
    const int*   eidx = (const int*)d_in[1];     // [2,E]
    const float* ew   = (const float*)d_in[2];   // [E]
    const int*   batch= (const int*)d_in[3];     // [N]
    const float* W1   = (const float*)d_in[4];
    const float* b1   = (const float*)d_in[5];
    const float* W2   = (const float*)d_in[6];
    const float* b2   = (const float*)d_in[7];
    const float* W3   = (const float*)d_in[8];
    const float* b3   = (const float*)d_in[9];
    const float* Wout = (const float*)d_in[10];
    const float* bout = (const float*)d_in[11];
    float* out = (float*)d_out;

    const int N = in_sizes[0] / 16;  // 100000
    const int E = in_sizes[2];       // 3200000
    const int G = out_size;          // 64
    const int* src = eidx;
    const int* dst = eidx + E;

    // workspace carve-up (256B-aligned slabs)
    size_t off = 0;
    auto carve = [&](size_t bytes) -> void* {
        void* p = (char*)d_ws + off;
        off += (bytes + 255) & ~(size_t)255;
        return p;
    };
    float* deg      = (float*)carve((size_t)N * 4);        // -> dinv in place
    int*   cnt      = (int*)  carve((size_t)N * 4);
    float* psum     = (float*)carve(64 * 4);
    float* pcnt     = (float*)carve(64 * 4);
    size_t zero_bytes = off;                               // region needing zeros
    int*   row_start= (int*)  carve((size_t)(N + 1) * 4);
    int*   cursor   = (int*)  carve((size_t)N * 4);
    int*   csr_src  = (int*)  carve((size_t)E * 4);
    float* csr_w    = (float*)carve((size_t)E * 4);
    float* bufA     = (float*)carve((size_t)N * HID * 4);  // h (pre-agg)
    float* bufB     = (float*)carve((size_t)N * HID * 4);  // agg output
    (void)ws_size;

    hipMemsetAsync(d_ws, 0, zero_bytes, stream);

    const int nodeBlocks = (N + 3) / 4;      // wave-per-node kernels
    const int edgeBlocks = 8192;             // grid-stride over edges

    // --- degree + CSR build (once; normalized weights shared by all layers) ---
    k_hist<<<edgeBlocks, 256, 0, stream>>>(dst, ew, deg, cnt, E);
    k_dinv<<<(N + 255) / 256, 256, 0, stream>>>(deg, N);
    k_scan<<<1, 1024, 0, stream>>>(cnt, row_start, cursor, N);
    k_scatter<<<edgeBlocks, 256, 0, stream>>>(src, dst, ew, deg, cursor,
                                              csr_src, csr_w, E);

    // --- layer 1: h = x @ W1 ; agg ---
    k_mm<16, false><<<2048, 256, 0, stream>>>(x, W1, bufA, N);
    k_agg<<<nodeBlocks, 256, 0, stream>>>(bufA, b1, deg, row_start, csr_src,
                                          csr_w, bufB, N);
    // --- layer 2: h = sigmoid(agg1) @ W2 ; agg ---
    k_mm<64, true><<<2048, 256, 0, stream>>>(bufB, W2, bufA, N);
    k_agg<<<nodeBlocks, 256, 0, stream>>>(bufA, b2, deg, row_start, csr_src,
                                          csr_w, bufB, N);
    // --- layer 3: h = sigmoid(agg2) @ W3 ; agg ---
    k_mm<64, true><<<2048, 256, 0, stream>>>(bufB, W3, bufA, N);
    k_agg<<<nodeBlocks, 256, 0, stream>>>(bufA, b3, deg, row_start, csr_src,
                                          csr_w, bufB, N);

    // --- mean-pool + head ---
    k_pool<<<nodeBlocks, 256, 0, stream>>>(bufB, batch, Wout, psum, pcnt, N);
    k_out<<<1, 64, 0, stream>>>(psum, pcnt, bout, out, G);
}

// Round 2
// 1153.900 us; speedup vs baseline: 1.7043x; 1.7043x over previous
//
#include <hip/hip_runtime.h>
#include <hip/hip_bf16.h>

#define HID 64

// ---------------------------------------------------------------------------
// K1: histogram — per edge: deg_w[dst] += ew ; cnt[dst] += 1
// ---------------------------------------------------------------------------
__global__ __launch_bounds__(256) void k_hist(const int* __restrict__ dst,
                                              const float* __restrict__ ew,
                                              float* __restrict__ deg,
                                              int* __restrict__ cnt, int nE) {
    int i = blockIdx.x * blockDim.x + threadIdx.x;
    int stride = gridDim.x * blockDim.x;
    for (; i < nE; i += stride) {
        int d = dst[i];
        atomicAdd(&deg[d], ew[i]);
        atomicAdd(&cnt[d], 1);
    }
}

// ---------------------------------------------------------------------------
// K2: dinv — deg -> rsqrt(deg + 1) in place
// ---------------------------------------------------------------------------
__global__ __launch_bounds__(256) void k_dinv(float* __restrict__ deg, int n) {
    int i = blockIdx.x * blockDim.x + threadIdx.x;
    if (i < n) {
        float d = deg[i] + 1.0f;
        deg[i] = rsqrtf(fmaxf(d, 1e-12f));
    }
}

// ---------------------------------------------------------------------------
// K3: single-block exclusive scan of cnt -> row_start[0..n] + cursor copy
// ---------------------------------------------------------------------------
__global__ __launch_bounds__(1024) void k_scan(const int* __restrict__ cnt,
                                               int* __restrict__ row_start,
                                               int* __restrict__ cursor, int n) {
    __shared__ int wsum[16];
    __shared__ int woff[16];
    __shared__ int carry_s;
    int tid = threadIdx.x;
    int lane = tid & 63, wv = tid >> 6;
    if (tid == 0) carry_s = 0;
    __syncthreads();
    const int CHUNK = 4096;
    for (int base = 0; base < n; base += CHUNK) {
        int idx0 = base + tid * 4;
        int v[4], local = 0;
#pragma unroll
        for (int j = 0; j < 4; ++j) {
            int i = idx0 + j;
            v[j] = (i < n) ? cnt[i] : 0;
            local += v[j];
        }
        int sc = local;
#pragma unroll
        for (int off = 1; off < 64; off <<= 1) {
            int t = __shfl_up(sc, off);
            if (lane >= off) sc += t;
        }
        if (lane == 63) wsum[wv] = sc;
        __syncthreads();
        if (tid == 0) {
            int acc = 0;
#pragma unroll
            for (int w = 0; w < 16; ++w) { woff[w] = acc; acc += wsum[w]; }
            wsum[0] = acc;
        }
        __syncthreads();
        int excl = carry_s + woff[wv] + sc - local;
#pragma unroll
        for (int j = 0; j < 4; ++j) {
            int i = idx0 + j;
            if (i < n) { row_start[i] = excl; cursor[i] = excl; }
            excl += v[j];
        }
        int total = wsum[0];
        __syncthreads();
        if (tid == 0) carry_s += total;
        __syncthreads();
    }
    if (tid == 0) row_start[n] = carry_s;
}

// ---------------------------------------------------------------------------
// K4: scatter edges into CSR as packed (src, weight) int2 — one 8B store/edge
//     w = dinv[src] * ew * dinv[dst]   (reused by all 3 layers)
// ---------------------------------------------------------------------------
__global__ __launch_bounds__(256) void k_scatter(const int* __restrict__ src,
                                                 const int* __restrict__ dst,
                                                 const float* __restrict__ ew,
                                                 const float* __restrict__ dinv,
                                                 int* __restrict__ cursor,
                                                 int2* __restrict__ csr, int nE) {
    int i = blockIdx.x * blockDim.x + threadIdx.x;
    int stride = gridDim.x * blockDim.x;
    for (; i < nE; i += stride) {
        int s = src[i], d = dst[i];
        float w = dinv[s] * ew[i] * dinv[d];
        int pos = atomicAdd(&cursor[d], 1);
        int2 sw;
        sw.x = s;
        sw.y = __float_as_int(w);
        csr[pos] = sw;
    }
}

// ---------------------------------------------------------------------------
// K5: layer-1 matmul  h1[n][f] = sum_k x[n][k] * W1[k][f]   (f = lane)
// ---------------------------------------------------------------------------
__global__ __launch_bounds__(256) void k_mm16(const float* __restrict__ in,
                                              const float* __restrict__ W,
                                              float* __restrict__ out, int n_nodes) {
    __shared__ float Ws[16 * HID];
    for (int i = threadIdx.x; i < 16 * HID; i += blockDim.x) Ws[i] = W[i];
    __syncthreads();
    int lane = threadIdx.x & 63;
    int wid = threadIdx.x >> 6;
    int wavesTotal = gridDim.x * (blockDim.x >> 6);
    for (int node = blockIdx.x * (blockDim.x >> 6) + wid; node < n_nodes;
         node += wavesTotal) {
        float xr = (lane < 16) ? in[node * 16 + lane] : 0.0f;
        float acc = 0.0f;
#pragma unroll
        for (int k = 0; k < 16; ++k) {
            float xv = __shfl(xr, k);
            acc = fmaf(xv, Ws[k * HID + lane], acc);
        }
        out[node * HID + lane] = acc;
    }
}

// ---------------------------------------------------------------------------
// K6: fused aggregation — wave per node, lane = feature.
//     a = b[f] + h[n][f]*dinv[n]^2 + sum_{e in row n} h[src_e][f]*w_e
//     EPI==1: out[n][f] = sum_k sigmoid(a_k) * Wn[k][f]   (next layer's h)
//     EPI==2: out[n]    = sum_f a_f * Wn[f]               (pooling scalar)
// ---------------------------------------------------------------------------
template <int EPI>
__global__ __launch_bounds__(256) void k_aggmm(const float* __restrict__ h,
                                               const float* __restrict__ bias,
                                               const float* __restrict__ dinv,
                                               const int* __restrict__ row_start,
                                               const int2* __restrict__ csr,
                                               const float* __restrict__ Wn,
                                               float* __restrict__ out, int n_nodes) {
    __shared__ float Ws[(EPI == 1) ? HID * HID : 64];
    if (EPI == 1) {
        for (int i = threadIdx.x; i < HID * HID; i += blockDim.x) Ws[i] = Wn[i];
        __syncthreads();
    }
    int lane = threadIdx.x & 63;
    int wid = threadIdx.x >> 6;
    int node = blockIdx.x * 4 + wid;
    if (node >= n_nodes) return;
    float di = dinv[node];
    float acc = bias[lane] + h[node * HID + lane] * di * di;
    int e0 = row_start[node], e1 = row_start[node + 1];
    for (int base = e0; base < e1; base += 64) {
        int m = min(64, e1 - base);
        int s = 0;
        float w = 0.0f;
        if (lane < m) {
            int2 sw = csr[base + lane];
            s = sw.x;
            w = __int_as_float(sw.y);
        }
        int j = 0;
        for (; j + 4 <= m; j += 4) {
            int s0 = __shfl(s, j), s1 = __shfl(s, j + 1);
            int s2 = __shfl(s, j + 2), s3 = __shfl(s, j + 3);
            float w0 = __shfl(w, j), w1 = __shfl(w, j + 1);
            float w2 = __shfl(w, j + 2), w3 = __shfl(w, j + 3);
            float h0 = h[s0 * HID + lane];
            float h1 = h[s1 * HID + lane];
            float h2 = h[s2 * HID + lane];
            float h3 = h[s3 * HID + lane];
            acc = fmaf(h0, w0, acc);
            acc = fmaf(h1, w1, acc);
            acc = fmaf(h2, w2, acc);
            acc = fmaf(h3, w3, acc);
        }
        for (; j < m; ++j) {
            int sj = __shfl(s, j);
            float wj = __shfl(w, j);
            acc = fmaf(h[sj * HID + lane], wj, acc);
        }
    }
    if (EPI == 1) {
        float sg = 1.0f / (1.0f + __expf(-acc));
        float o = 0.0f;
#pragma unroll
        for (int k = 0; k < HID; ++k) {
            float xv = __shfl(sg, k);
            o = fmaf(xv, Ws[k * HID + lane], o);
        }
        out[node * HID + lane] = o;
    } else {
        float v = acc * Wn[lane];
#pragma unroll
        for (int off = 32; off; off >>= 1) v += __shfl_xor(v, off);
        if (lane == 0) out[node] = v;
    }
}

// ---------------------------------------------------------------------------
// K7: segmented pool over sorted batch — wave handles 64 consecutive nodes.
//     Uniform graph id (the common case): ONE atomic per wave.
// ---------------------------------------------------------------------------
__global__ __launch_bounds__(256) void k_poolseg(const float* __restrict__ p,
                                                 const int* __restrict__ batch,
                                                 float* __restrict__ psum,
                                                 float* __restrict__ pcnt,
                                                 int n_nodes) {
    int lane = threadIdx.x & 63;
    int gw = (blockIdx.x * blockDim.x + threadIdx.x) >> 6;  // global wave id
    int node = gw * 64 + lane;
    bool valid = node < n_nodes;
    float v = valid ? p[node] : 0.0f;
    int g = valid ? batch[node] : -1;
    int g0 = __shfl(g, 0);
    if (__all((g == g0) && valid)) {
#pragma unroll
        for (int off = 32; off; off >>= 1) v += __shfl_xor(v, off);
        if (lane == 0) {
            atomicAdd(&psum[g0], v);
            atomicAdd(&pcnt[g0], 64.0f);
        }
    } else if (valid) {
        atomicAdd(&psum[g], v);
        atomicAdd(&pcnt[g], 1.0f);
    }
}

// K8: final — out[g] = psum[g]/max(pcnt[g],1) + bout
__global__ __launch_bounds__(64) void k_out(const float* __restrict__ psum,
                                            const float* __restrict__ pcnt,
                                            const float* __restrict__ bout,
                                            float* __restrict__ out, int G) {
    int g = threadIdx.x;
    if (g < G) out[g] = psum[g] / fmaxf(pcnt[g], 1.0f) + bout[0];
}

extern "C" void kernel_launch(void* const* d_in, const int* in_sizes, int n_in,
                              void* d_out, int out_size, void* d_ws, size_t ws_size,
                              hipStream_t stream) {
    const float* x    = (const float*)d_in[0];   // [N,16]
    const int*   eidx = (const int*)d_in[1];     // [2,E]
    const float* ew   = (const float*)d_in[2];   // [E]
    const int*   batch= (const int*)d_in[3];     // [N]
    const float* W1   = (const float*)d_in[4];
    const float* b1   = (const float*)d_in[5];
    const float* W2   = (const float*)d_in[6];
    const float* b2   = (const float*)d_in[7];
    const float* W3   = (const float*)d_in[8];
    const float* b3   = (const float*)d_in[9];
    const float* Wout = (const float*)d_in[10];
    const float* bout = (const float*)d_in[11];
    float* out = (float*)d_out;

    const int N = in_sizes[0] / 16;  // 100000
    const int E = in_sizes[2];       // 3200000
    const int G = out_size;          // 64
    const int* src = eidx;
    const int* dst = eidx + E;

    size_t off = 0;
    auto carve = [&](size_t bytes) -> void* {
        void* p = (char*)d_ws + off;
        off += (bytes + 255) & ~(size_t)255;
        return p;
    };
    float* deg      = (float*)carve((size_t)N * 4);        // -> dinv in place
    int*   cnt      = (int*)  carve((size_t)N * 4);
    float* psum     = (float*)carve(64 * 4);
    float* pcnt     = (float*)carve(64 * 4);
    size_t zero_bytes = off;                               // region needing zeros
    int*   row_start= (int*)  carve((size_t)(N + 1) * 4);
    int*   cursor   = (int*)  carve((size_t)N * 4);
    int2*  csr      = (int2*) carve((size_t)E * 8);
    float* bufA     = (float*)carve((size_t)N * HID * 4);
    float* bufB     = (float*)carve((size_t)N * HID * 4);
    float* p        = bufB;  // reuse: aggmm<2> reads bufA, writes scalar p
    (void)ws_size;

    hipMemsetAsync(d_ws, 0, zero_bytes, stream);

    const int nodeBlocks = (N + 3) / 4;
    const int edgeBlocks = 8192;
    const int waveBlocks = ((N + 63) / 64 * 64 + 255) / 256;

    // --- degree + CSR build (once; normalized weights shared by all layers) ---
    k_hist<<<edgeBlocks, 256, 0, stream>>>(dst, ew, deg, cnt, E);
    k_dinv<<<(N + 255) / 256, 256, 0, stream>>>(deg, N);
    k_scan<<<1, 1024, 0, stream>>>(cnt, row_start, cursor, N);
    k_scatter<<<edgeBlocks, 256, 0, stream>>>(src, dst, ew, deg, cursor, csr, E);

    // --- layer 1 matmul ---
    k_mm16<<<2048, 256, 0, stream>>>(x, W1, bufA, N);
    // --- agg1 + sigmoid + @W2 fused ---
    k_aggmm<1><<<nodeBlocks, 256, 0, stream>>>(bufA, b1, deg, row_start, csr,
                                               W2, bufB, N);
    // --- agg2 + sigmoid + @W3 fused ---
    k_aggmm<1><<<nodeBlocks, 256, 0, stream>>>(bufB, b2, deg, row_start, csr,
                                               W3, bufA, N);
    // --- agg3 + dot(Wout) fused -> per-node scalar p ---
    k_aggmm<2><<<nodeBlocks, 256, 0, stream>>>(bufA, b3, deg, row_start, csr,
                                               Wout, p, N);

    // --- segmented mean-pool (sorted batch) + head ---
    k_poolseg<<<waveBlocks, 256, 0, stream>>>(p, batch, psum, pcnt, N);
    k_out<<<1, 64, 0, stream>>>(psum, pcnt, bout, out, G);
}

// Round 3
// 775.267 us; speedup vs baseline: 2.5366x; 1.4884x over previous
//
#include <hip/hip_runtime.h>
#include <hip/hip_bf16.h>

#define HID 64

// ---------------------------------------------------------------------------
// K1: rank pass — r[i] = old cnt[dst[i]]++  (the ONLY atomic pass over edges)
// ---------------------------------------------------------------------------
__global__ __launch_bounds__(256) void k_rank(const int* __restrict__ dst,
                                              int* __restrict__ cnt,
                                              int* __restrict__ rnk, int nE) {
    int i = blockIdx.x * blockDim.x + threadIdx.x;
    if (i < nE) rnk[i] = atomicAdd(&cnt[dst[i]], 1);
}

// ---------------------------------------------------------------------------
// K2: single-block exclusive scan of cnt -> row_start[0..n]
// ---------------------------------------------------------------------------
__global__ __launch_bounds__(1024) void k_scan(const int* __restrict__ cnt,
                                               int* __restrict__ row_start, int n) {
    __shared__ int wsum[16];
    __shared__ int woff[16];
    __shared__ int carry_s;
    int tid = threadIdx.x;
    int lane = tid & 63, wv = tid >> 6;
    if (tid == 0) carry_s = 0;
    __syncthreads();
    const int CHUNK = 4096;
    for (int base = 0; base < n; base += CHUNK) {
        int idx0 = base + tid * 4;
        int v[4], local = 0;
#pragma unroll
        for (int j = 0; j < 4; ++j) {
            int i = idx0 + j;
            v[j] = (i < n) ? cnt[i] : 0;
            local += v[j];
        }
        int sc = local;
#pragma unroll
        for (int off = 1; off < 64; off <<= 1) {
            int t = __shfl_up(sc, off);
            if (lane >= off) sc += t;
        }
        if (lane == 63) wsum[wv] = sc;
        __syncthreads();
        if (tid == 0) {
            int acc = 0;
#pragma unroll
            for (int w = 0; w < 16; ++w) { woff[w] = acc; acc += wsum[w]; }
            wsum[0] = acc;
        }
        __syncthreads();
        int excl = carry_s + woff[wv] + sc - local;
#pragma unroll
        for (int j = 0; j < 4; ++j) {
            int i = idx0 + j;
            if (i < n) row_start[i] = excl;
            excl += v[j];
        }
        int total = wsum[0];
        __syncthreads();
        if (tid == 0) carry_s += total;
        __syncthreads();
    }
    if (tid == 0) row_start[n] = carry_s;
}

// ---------------------------------------------------------------------------
// K3: placement — pos = row_start[dst] + rank; csr[pos] = (src, raw ew).
//     NO atomics. One random 8B store per edge.
// ---------------------------------------------------------------------------
__global__ __launch_bounds__(256) void k_place(const int* __restrict__ src,
                                               const int* __restrict__ dst,
                                               const float* __restrict__ ew,
                                               const int* __restrict__ row_start,
                                               const int* __restrict__ rnk,
                                               int2* __restrict__ csr, int nE) {
    int i = blockIdx.x * blockDim.x + threadIdx.x;
    if (i < nE) {
        int pos = row_start[dst[i]] + rnk[i];
        int2 sw;
        sw.x = src[i];
        sw.y = __float_as_int(ew[i]);
        csr[pos] = sw;
    }
}

// ---------------------------------------------------------------------------
// K4: deg/dinv from CSR — wave per node, coalesced row sum, atomic-free.
//     dinv[n] = rsqrt(sum(ew over row) + 1)
// ---------------------------------------------------------------------------
__global__ __launch_bounds__(256) void k_degdinv(const int* __restrict__ row_start,
                                                 const int2* __restrict__ csr,
                                                 float* __restrict__ dinv,
                                                 int n_nodes) {
    int lane = threadIdx.x & 63;
    int wid = threadIdx.x >> 6;
    int node = blockIdx.x * 4 + wid;
    if (node >= n_nodes) return;
    int e0 = row_start[node], e1 = row_start[node + 1];
    float sum = 0.0f;
    for (int e = e0 + lane; e < e1; e += 64) sum += __int_as_float(csr[e].y);
#pragma unroll
    for (int off = 32; off; off >>= 1) sum += __shfl_xor(sum, off);
    if (lane == 0) dinv[node] = rsqrtf(fmaxf(sum + 1.0f, 1e-12f));
}

// ---------------------------------------------------------------------------
// K5: layer-1 matmul, prescaled bf16 output: g1[n][f] = (x[n]@W1)[f] * dinv[n]
// ---------------------------------------------------------------------------
__global__ __launch_bounds__(256) void k_mm16(const float* __restrict__ in,
                                              const float* __restrict__ W,
                                              const float* __restrict__ dinv,
                                              __hip_bfloat16* __restrict__ out,
                                              int n_nodes) {
    __shared__ float Ws[16 * HID];
    for (int i = threadIdx.x; i < 16 * HID; i += blockDim.x) Ws[i] = W[i];
    __syncthreads();
    int lane = threadIdx.x & 63;
    int wid = threadIdx.x >> 6;
    int wavesTotal = gridDim.x * (blockDim.x >> 6);
    for (int node = blockIdx.x * (blockDim.x >> 6) + wid; node < n_nodes;
         node += wavesTotal) {
        float xr = (lane < 16) ? in[node * 16 + lane] : 0.0f;
        float acc = 0.0f;
#pragma unroll
        for (int k = 0; k < 16; ++k) {
            float xv = __shfl(xr, k);
            acc = fmaf(xv, Ws[k * HID + lane], acc);
        }
        out[node * HID + lane] = __float2bfloat16(acc * dinv[node]);
    }
}

// ---------------------------------------------------------------------------
// K6: fused aggregation — wave per node; 2 edges in flight (one per half-wave);
//     g stored bf16-packed (uint = features 2p|2p+1), fp32 accumulate.
//     a_f = b[f] + dinv[d]*(g[d][f] + sum_e ew_e * g[src_e][f])
//     EPI==1: out = bf16( (sigmoid(a) @ Wn) * dinv[d] )   [next layer's g]
//     EPI==2: out[d] = dot(a, Wn)                          [pooling scalar]
// ---------------------------------------------------------------------------
template <int EPI>
__global__ __launch_bounds__(256) void k_aggmm(const unsigned int* __restrict__ gb,
                                               const float* __restrict__ bias,
                                               const float* __restrict__ dinv,
                                               const int* __restrict__ row_start,
                                               const int2* __restrict__ csr,
                                               const float* __restrict__ Wn,
                                               void* __restrict__ outv,
                                               int n_nodes) {
    __shared__ float Ws[(EPI == 1) ? HID * HID : 64];
    if (EPI == 1) {
        for (int i = threadIdx.x; i < HID * HID; i += blockDim.x) Ws[i] = Wn[i];
        __syncthreads();
    }
    int lane = threadIdx.x & 63;
    int wid = threadIdx.x >> 6;
    int node = blockIdx.x * 4 + wid;
    if (node >= n_nodes) return;
    int p = lane & 31;
    int half = lane >> 5;

    // self term (g[node], weight 1) into half 0 only
    unsigned su = gb[node * 32 + p];
    float2 acc;
    acc.x = half ? 0.0f : __uint_as_float(su << 16);
    acc.y = half ? 0.0f : __uint_as_float(su & 0xffff0000u);

    int e0 = row_start[node], e1 = row_start[node + 1];
    for (int base = e0; base < e1; base += 64) {
        int m = min(64, e1 - base);
        int s = 0;
        float w = 0.0f;
        if (lane < m) {
            int2 sw = csr[base + lane];
            s = sw.x;
            w = __int_as_float(sw.y);
        }
        int npair = (m + 1) >> 1;
        int j = 0;
        for (; j + 4 <= npair; j += 4) {  // 4 pairs = 8 edges
            int sh0 = __shfl(s, 2 * j + half);
            float wh0 = __shfl(w, 2 * j + half);
            int sh1 = __shfl(s, 2 * j + 2 + half);
            float wh1 = __shfl(w, 2 * j + 2 + half);
            int sh2 = __shfl(s, 2 * j + 4 + half);
            float wh2 = __shfl(w, 2 * j + 4 + half);
            int sh3 = __shfl(s, 2 * j + 6 + half);
            float wh3 = __shfl(w, 2 * j + 6 + half);
            unsigned u0 = gb[sh0 * 32 + p];
            unsigned u1 = gb[sh1 * 32 + p];
            unsigned u2 = gb[sh2 * 32 + p];
            unsigned u3 = gb[sh3 * 32 + p];
            acc.x = fmaf(__uint_as_float(u0 << 16), wh0, acc.x);
            acc.y = fmaf(__uint_as_float(u0 & 0xffff0000u), wh0, acc.y);
            acc.x = fmaf(__uint_as_float(u1 << 16), wh1, acc.x);
            acc.y = fmaf(__uint_as_float(u1 & 0xffff0000u), wh1, acc.y);
            acc.x = fmaf(__uint_as_float(u2 << 16), wh2, acc.x);
            acc.y = fmaf(__uint_as_float(u2 & 0xffff0000u), wh2, acc.y);
            acc.x = fmaf(__uint_as_float(u3 << 16), wh3, acc.x);
            acc.y = fmaf(__uint_as_float(u3 & 0xffff0000u), wh3, acc.y);
        }
        for (; j < npair; ++j) {
            int sh = __shfl(s, 2 * j + half);
            float wh = __shfl(w, 2 * j + half);
            unsigned u = gb[sh * 32 + p];
            acc.x = fmaf(__uint_as_float(u << 16), wh, acc.x);
            acc.y = fmaf(__uint_as_float(u & 0xffff0000u), wh, acc.y);
        }
    }
    // fold halves: every lane now has the full edge+self sum for features 2p,2p+1
    acc.x += __shfl_xor(acc.x, 32);
    acc.y += __shfl_xor(acc.y, 32);
    float di = dinv[node];
    float2 b2v = ((const float2*)bias)[p];
    float ax = fmaf(di, acc.x, b2v.x);
    float ay = fmaf(di, acc.y, b2v.y);

    if (EPI == 1) {
        float sgx = 1.0f / (1.0f + __expf(-ax));
        float sgy = 1.0f / (1.0f + __expf(-ay));
        float o = 0.0f;
#pragma unroll
        for (int q = 0; q < 32; ++q) {
            float vx = __shfl(sgx, q);  // feature 2q
            float vy = __shfl(sgy, q);  // feature 2q+1
            o = fmaf(vx, Ws[(2 * q) * HID + lane], o);
            o = fmaf(vy, Ws[(2 * q + 1) * HID + lane], o);
        }
        ((__hip_bfloat16*)outv)[node * HID + lane] = __float2bfloat16(o * di);
    } else {
        float2 w2 = ((const float2*)Wn)[p];
        float v = ax * w2.x + ay * w2.y;
#pragma unroll
        for (int off = 16; off; off >>= 1) v += __shfl_xor(v, off);  // per-half reduce
        if (lane == 0) ((float*)outv)[node] = v;
    }
}

// ---------------------------------------------------------------------------
// K7: segmented pool over sorted batch — one atomic per uniform 64-node wave
// ---------------------------------------------------------------------------
__global__ __launch_bounds__(256) void k_poolseg(const float* __restrict__ p,
                                                 const int* __restrict__ batch,
                                                 float* __restrict__ psum,
                                                 float* __restrict__ pcnt,
                                                 int n_nodes) {
    int lane = threadIdx.x & 63;
    int gw = (blockIdx.x * blockDim.x + threadIdx.x) >> 6;
    int node = gw * 64 + lane;
    bool valid = node < n_nodes;
    float v = valid ? p[node] : 0.0f;
    int g = valid ? batch[node] : -1;
    int g0 = __shfl(g, 0);
    if (__all((g == g0) && valid)) {
#pragma unroll
        for (int off = 32; off; off >>= 1) v += __shfl_xor(v, off);
        if (lane == 0) {
            atomicAdd(&psum[g0], v);
            atomicAdd(&pcnt[g0], 64.0f);
        }
    } else if (valid) {
        atomicAdd(&psum[g], v);
        atomicAdd(&pcnt[g], 1.0f);
    }
}

// K8: final — out[g] = psum[g]/max(pcnt[g],1) + bout
__global__ __launch_bounds__(64) void k_out(const float* __restrict__ psum,
                                            const float* __restrict__ pcnt,
                                            const float* __restrict__ bout,
                                            float* __restrict__ out, int G) {
    int g = threadIdx.x;
    if (g < G) out[g] = psum[g] / fmaxf(pcnt[g], 1.0f) + bout[0];
}

extern "C" void kernel_launch(void* const* d_in, const int* in_sizes, int n_in,
                              void* d_out, int out_size, void* d_ws, size_t ws_size,
                              hipStream_t stream) {
    const float* x    = (const float*)d_in[0];   // [N,16]
    const int*   eidx = (const int*)d_in[1];     // [2,E]
    const float* ew   = (const float*)d_in[2];   // [E]
    const int*   batch= (const int*)d_in[3];     // [N]
    const float* W1   = (const float*)d_in[4];
    const float* b1   = (const float*)d_in[5];
    const float* W2   = (const float*)d_in[6];
    const float* b2   = (const float*)d_in[7];
    const float* W3   = (const float*)d_in[8];
    const float* b3   = (const float*)d_in[9];
    const float* Wout = (const float*)d_in[10];
    const float* bout = (const float*)d_in[11];
    float* out = (float*)d_out;

    const int N = in_sizes[0] / 16;  // 100000
    const int E = in_sizes[2];       // 3200000
    const int G = out_size;          // 64
    const int* src = eidx;
    const int* dst = eidx + E;

    size_t off = 0;
    auto carve = [&](size_t bytes) -> void* {
        void* p = (char*)d_ws + off;
        off += (bytes + 255) & ~(size_t)255;
        return p;
    };
    int*   cnt      = (int*)  carve((size_t)N * 4);
    float* psum     = (float*)carve(64 * 4);
    float* pcnt     = (float*)carve(64 * 4);
    size_t zero_bytes = off;                               // zeroed region
    int*   row_start= (int*)  carve((size_t)(N + 1) * 4);
    int*   rnk      = (int*)  carve((size_t)E * 4);
    int2*  csr      = (int2*) carve((size_t)E * 8);
    float* dinv     = (float*)carve((size_t)N * 4);
    __hip_bfloat16* gA = (__hip_bfloat16*)carve((size_t)N * HID * 2);
    __hip_bfloat16* gB = (__hip_bfloat16*)carve((size_t)N * HID * 2);
    float* p        = (float*)gB;  // agg3 reads gA, writes scalar p over gB
    (void)ws_size;

    hipMemsetAsync(d_ws, 0, zero_bytes, stream);

    const int nodeBlocks = (N + 3) / 4;
    const int edgeBlocks = (E + 255) / 256;
    const int waveBlocks = ((N + 63) / 64 * 64 + 255) / 256;

    // --- CSR build: one atomic pass + scan + atomic-free placement ---
    k_rank<<<edgeBlocks, 256, 0, stream>>>(dst, cnt, rnk, E);
    k_scan<<<1, 1024, 0, stream>>>(cnt, row_start, N);
    k_place<<<edgeBlocks, 256, 0, stream>>>(src, dst, ew, row_start, rnk, csr, E);
    k_degdinv<<<nodeBlocks, 256, 0, stream>>>(row_start, csr, dinv, N);

    // --- layer 1 matmul (prescaled bf16 g1) ---
    k_mm16<<<2048, 256, 0, stream>>>(x, W1, dinv, gA, N);
    // --- agg1 + sigmoid + @W2 (+dinv prescale) ---
    k_aggmm<1><<<nodeBlocks, 256, 0, stream>>>((const unsigned*)gA, b1, dinv,
                                               row_start, csr, W2, gB, N);
    // --- agg2 + sigmoid + @W3 (+dinv prescale) ---
    k_aggmm<1><<<nodeBlocks, 256, 0, stream>>>((const unsigned*)gB, b2, dinv,
                                               row_start, csr, W3, gA, N);
    // --- agg3 + dot(Wout) -> per-node scalar ---
    k_aggmm<2><<<nodeBlocks, 256, 0, stream>>>((const unsigned*)gA, b3, dinv,
                                               row_start, csr, Wout, p, N);

    // --- segmented mean-pool (sorted batch) + head ---
    k_poolseg<<<waveBlocks, 256, 0, stream>>>(p, batch, psum, pcnt, N);
    k_out<<<1, 64, 0, stream>>>(psum, pcnt, bout, out, G);
}

// Round 4
// 736.272 us; speedup vs baseline: 2.6710x; 1.0530x over previous
//
#include <hip/hip_runtime.h>
#include <hip/hip_bf16.h>

#define HID 64

typedef float v2f __attribute__((ext_vector_type(2)));

// HW fp8 (gfx950: OCP e4m3) conversions — self-consistent pack/unpack.
__device__ inline v2f fp8x2_lo(unsigned u) { return __builtin_amdgcn_cvt_pk_f32_fp8(u, false); }
__device__ inline v2f fp8x2_hi(unsigned u) { return __builtin_amdgcn_cvt_pk_f32_fp8(u, true); }
__device__ inline unsigned char f32_fp8(float a) {
    return (unsigned char)(__builtin_amdgcn_cvt_pk_fp8_f32(a, a, 0, false) & 0xff);
}

#define GSCALE 16.0f
#define GINV 0.0625f

// ---------------------------------------------------------------------------
// K1: rank pass — r[i] = old cnt[dst[i]]++  (the ONLY atomic pass over edges)
// ---------------------------------------------------------------------------
__global__ __launch_bounds__(256) void k_rank(const int* __restrict__ dst,
                                              int* __restrict__ cnt,
                                              unsigned short* __restrict__ rnk, int nE) {
    int i = blockIdx.x * blockDim.x + threadIdx.x;
    if (i < nE) rnk[i] = (unsigned short)atomicAdd(&cnt[dst[i]], 1);
}

// ---------------------------------------------------------------------------
// K2: single-block exclusive scan of cnt -> row_start[0..n]
// ---------------------------------------------------------------------------
__global__ __launch_bounds__(1024) void k_scan(const int* __restrict__ cnt,
                                               int* __restrict__ row_start, int n) {
    __shared__ int wsum[16];
    __shared__ int woff[16];
    __shared__ int carry_s;
    int tid = threadIdx.x;
    int lane = tid & 63, wv = tid >> 6;
    if (tid == 0) carry_s = 0;
    __syncthreads();
    const int CHUNK = 4096;
    for (int base = 0; base < n; base += CHUNK) {
        int idx0 = base + tid * 4;
        int v[4], local = 0;
#pragma unroll
        for (int j = 0; j < 4; ++j) {
            int i = idx0 + j;
            v[j] = (i < n) ? cnt[i] : 0;
            local += v[j];
        }
        int sc = local;
#pragma unroll
        for (int off = 1; off < 64; off <<= 1) {
            int t = __shfl_up(sc, off);
            if (lane >= off) sc += t;
        }
        if (lane == 63) wsum[wv] = sc;
        __syncthreads();
        if (tid == 0) {
            int acc = 0;
#pragma unroll
            for (int w = 0; w < 16; ++w) { woff[w] = acc; acc += wsum[w]; }
            wsum[0] = acc;
        }
        __syncthreads();
        int excl = carry_s + woff[wv] + sc - local;
#pragma unroll
        for (int j = 0; j < 4; ++j) {
            int i = idx0 + j;
            if (i < n) row_start[i] = excl;
            excl += v[j];
        }
        int total = wsum[0];
        __syncthreads();
        if (tid == 0) carry_s += total;
        __syncthreads();
    }
    if (tid == 0) row_start[n] = carry_s;
}

// ---------------------------------------------------------------------------
// K3: placement — pos = row_start[dst] + rank; csr[pos] = (src, raw ew).
// ---------------------------------------------------------------------------
__global__ __launch_bounds__(256) void k_place(const int* __restrict__ src,
                                               const int* __restrict__ dst,
                                               const float* __restrict__ ew,
                                               const int* __restrict__ row_start,
                                               const unsigned short* __restrict__ rnk,
                                               int2* __restrict__ csr, int nE) {
    int i = blockIdx.x * blockDim.x + threadIdx.x;
    if (i < nE) {
        int pos = row_start[dst[i]] + (int)rnk[i];
        int2 sw;
        sw.x = src[i];
        sw.y = __float_as_int(ew[i]);
        csr[pos] = sw;
    }
}

// ---------------------------------------------------------------------------
// K4: deg/dinv from CSR — wave per node, coalesced row sum, atomic-free.
// ---------------------------------------------------------------------------
__global__ __launch_bounds__(256) void k_degdinv(const int* __restrict__ row_start,
                                                 const int2* __restrict__ csr,
                                                 float* __restrict__ dinv,
                                                 int n_nodes) {
    int lane = threadIdx.x & 63;
    int wid = threadIdx.x >> 6;
    int node = blockIdx.x * 4 + wid;
    if (node >= n_nodes) return;
    int e0 = row_start[node], e1 = row_start[node + 1];
    float sum = 0.0f;
    for (int e = e0 + lane; e < e1; e += 64) sum += __int_as_float(csr[e].y);
#pragma unroll
    for (int off = 32; off; off >>= 1) sum += __shfl_xor(sum, off);
    if (lane == 0) dinv[node] = rsqrtf(fmaxf(sum + 1.0f, 1e-12f));
}

// ---------------------------------------------------------------------------
// K5: layer-1 matmul, fp8 prescaled output: g1[n][f] = fp8((x[n]@W1)[f]*dinv*16)
// ---------------------------------------------------------------------------
__global__ __launch_bounds__(256) void k_mm16(const float* __restrict__ in,
                                              const float* __restrict__ W,
                                              const float* __restrict__ dinv,
                                              unsigned char* __restrict__ out,
                                              int n_nodes) {
    __shared__ float Ws[16 * HID];
    for (int i = threadIdx.x; i < 16 * HID; i += blockDim.x) Ws[i] = W[i];
    __syncthreads();
    int lane = threadIdx.x & 63;
    int wid = threadIdx.x >> 6;
    int wavesTotal = gridDim.x * (blockDim.x >> 6);
    for (int node = blockIdx.x * (blockDim.x >> 6) + wid; node < n_nodes;
         node += wavesTotal) {
        float xr = (lane < 16) ? in[node * 16 + lane] : 0.0f;
        float acc = 0.0f;
#pragma unroll
        for (int k = 0; k < 16; ++k) {
            float xv = __shfl(xr, k);
            acc = fmaf(xv, Ws[k * HID + lane], acc);
        }
        out[node * HID + lane] = f32_fp8(acc * dinv[node] * GSCALE);
    }
}

// ---------------------------------------------------------------------------
// K6: fused aggregation — wave per node; QUARTER-wave per edge (fp8 row = one
//     64B line; 16 lanes x 1 dword). 4 edges per wave-instruction, 4 groups
//     unrolled = 16 edges / 4 loads in flight. fp32 accumulate.
//     a_f = b[f] + dinv[d]/16*(g[d][f] + sum_e ew_e * g[src_e][f])
//     EPI==1: out = fp8( (sigmoid(a) @ Wn) * dinv[d] * 16 )   [next g]
//     EPI==2: out[d] = dot(a, Wn)                              [pool scalar]
// ---------------------------------------------------------------------------
template <int EPI>
__global__ __launch_bounds__(256) void k_aggmm(const unsigned int* __restrict__ g32,
                                               const float* __restrict__ bias,
                                               const float* __restrict__ dinv,
                                               const int* __restrict__ row_start,
                                               const int2* __restrict__ csr,
                                               const float* __restrict__ Wn,
                                               void* __restrict__ outv,
                                               int n_nodes) {
    __shared__ float Ws[(EPI == 1) ? HID * HID : 64];
    if (EPI == 1) {
        for (int i = threadIdx.x; i < HID * HID; i += blockDim.x) Ws[i] = Wn[i];
        __syncthreads();
    }
    int lane = threadIdx.x & 63;
    int wid = threadIdx.x >> 6;
    int node = blockIdx.x * 4 + wid;
    if (node >= n_nodes) return;
    int p = lane & 15;   // dword within fp8 row (features 4p..4p+3)
    int q = lane >> 4;   // quarter = edge slot within a group of 4

    float a0 = 0.0f, a1 = 0.0f, a2 = 0.0f, a3 = 0.0f;
    {   // self term (weight 1), quarter 0 only
        unsigned su = g32[node * 16 + p];
        if (q == 0) {
            v2f lo = fp8x2_lo(su), hi = fp8x2_hi(su);
            a0 = lo.x; a1 = lo.y; a2 = hi.x; a3 = hi.y;
        }
    }
    int e0 = row_start[node], e1 = row_start[node + 1];
    for (int base = e0; base < e1; base += 64) {
        int m = min(64, e1 - base);
        int s = 0;
        float w = 0.0f;
        if (lane < m) {
            int2 sw = csr[base + lane];
            s = sw.x;
            w = __int_as_float(sw.y);
        }
        int ng = (m + 3) >> 2;  // groups of 4 edges
        int j = 0;
        for (; j + 4 <= ng; j += 4) {  // 16 edges, 4 gathers in flight
            int eA = 4 * j + q;
            int sA = __shfl(s, eA);      float wA = __shfl(w, eA);
            int sB = __shfl(s, eA + 4);  float wB = __shfl(w, eA + 4);
            int sC = __shfl(s, eA + 8);  float wC = __shfl(w, eA + 8);
            int sD = __shfl(s, eA + 12); float wD = __shfl(w, eA + 12);
            unsigned uA = g32[sA * 16 + p];
            unsigned uB = g32[sB * 16 + p];
            unsigned uC = g32[sC * 16 + p];
            unsigned uD = g32[sD * 16 + p];
            v2f lo, hi;
            lo = fp8x2_lo(uA); hi = fp8x2_hi(uA);
            a0 = fmaf(lo.x, wA, a0); a1 = fmaf(lo.y, wA, a1);
            a2 = fmaf(hi.x, wA, a2); a3 = fmaf(hi.y, wA, a3);
            lo = fp8x2_lo(uB); hi = fp8x2_hi(uB);
            a0 = fmaf(lo.x, wB, a0); a1 = fmaf(lo.y, wB, a1);
            a2 = fmaf(hi.x, wB, a2); a3 = fmaf(hi.y, wB, a3);
            lo = fp8x2_lo(uC); hi = fp8x2_hi(uC);
            a0 = fmaf(lo.x, wC, a0); a1 = fmaf(lo.y, wC, a1);
            a2 = fmaf(hi.x, wC, a2); a3 = fmaf(hi.y, wC, a3);
            lo = fp8x2_lo(uD); hi = fp8x2_hi(uD);
            a0 = fmaf(lo.x, wD, a0); a1 = fmaf(lo.y, wD, a1);
            a2 = fmaf(hi.x, wD, a2); a3 = fmaf(hi.y, wD, a3);
        }
        for (; j < ng; ++j) {
            int e = 4 * j + q;   // e <= m+2 < 64; lanes >= m carry w=0, s=0
            int sA = __shfl(s, e);
            float wA = __shfl(w, e);
            unsigned uA = g32[sA * 16 + p];
            v2f lo = fp8x2_lo(uA), hi = fp8x2_hi(uA);
            a0 = fmaf(lo.x, wA, a0); a1 = fmaf(lo.y, wA, a1);
            a2 = fmaf(hi.x, wA, a2); a3 = fmaf(hi.y, wA, a3);
        }
    }
    // fold quarters: all lanes end with full sums for features 4p..4p+3
    a0 += __shfl_xor(a0, 16); a0 += __shfl_xor(a0, 32);
    a1 += __shfl_xor(a1, 16); a1 += __shfl_xor(a1, 32);
    a2 += __shfl_xor(a2, 16); a2 += __shfl_xor(a2, 32);
    a3 += __shfl_xor(a3, 16); a3 += __shfl_xor(a3, 32);

    float diRaw = dinv[node];
    float di = diRaw * GINV;  // undo GSCALE on the gathered table
    float4 bv = ((const float4*)bias)[p];
    a0 = fmaf(di, a0, bv.x);
    a1 = fmaf(di, a1, bv.y);
    a2 = fmaf(di, a2, bv.z);
    a3 = fmaf(di, a3, bv.w);

    if (EPI == 1) {
        a0 = 1.0f / (1.0f + __expf(-a0));
        a1 = 1.0f / (1.0f + __expf(-a1));
        a2 = 1.0f / (1.0f + __expf(-a2));
        a3 = 1.0f / (1.0f + __expf(-a3));
        float o = 0.0f;
#pragma unroll
        for (int k = 0; k < 16; ++k) {   // feature 4k+t lives at lane k (folded)
            o = fmaf(__shfl(a0, k), Ws[(4 * k + 0) * HID + lane], o);
            o = fmaf(__shfl(a1, k), Ws[(4 * k + 1) * HID + lane], o);
            o = fmaf(__shfl(a2, k), Ws[(4 * k + 2) * HID + lane], o);
            o = fmaf(__shfl(a3, k), Ws[(4 * k + 3) * HID + lane], o);
        }
        ((unsigned char*)outv)[node * HID + lane] = f32_fp8(o * diRaw * GSCALE);
    } else {
        float4 wv = ((const float4*)Wn)[p];
        float v = a0 * wv.x + a1 * wv.y + a2 * wv.z + a3 * wv.w;
        v += __shfl_xor(v, 1);
        v += __shfl_xor(v, 2);
        v += __shfl_xor(v, 4);
        v += __shfl_xor(v, 8);
        if (lane == 0) ((float*)outv)[node] = v;
    }
}

// ---------------------------------------------------------------------------
// K7: segmented pool over sorted batch — one atomic per uniform 64-node wave
// ---------------------------------------------------------------------------
__global__ __launch_bounds__(256) void k_poolseg(const float* __restrict__ p,
                                                 const int* __restrict__ batch,
                                                 float* __restrict__ psum,
                                                 float* __restrict__ pcnt,
                                                 int n_nodes) {
    int lane = threadIdx.x & 63;
    int gw = (blockIdx.x * blockDim.x + threadIdx.x) >> 6;
    int node = gw * 64 + lane;
    bool valid = node < n_nodes;
    float v = valid ? p[node] : 0.0f;
    int g = valid ? batch[node] : -1;
    int g0 = __shfl(g, 0);
    if (__all((g == g0) && valid)) {
#pragma unroll
        for (int off = 32; off; off >>= 1) v += __shfl_xor(v, off);
        if (lane == 0) {
            atomicAdd(&psum[g0], v);
            atomicAdd(&pcnt[g0], 64.0f);
        }
    } else if (valid) {
        atomicAdd(&psum[g], v);
        atomicAdd(&pcnt[g], 1.0f);
    }
}

// K8: final — out[g] = psum[g]/max(pcnt[g],1) + bout
__global__ __launch_bounds__(64) void k_out(const float* __restrict__ psum,
                                            const float* __restrict__ pcnt,
                                            const float* __restrict__ bout,
                                            float* __restrict__ out, int G) {
    int g = threadIdx.x;
    if (g < G) out[g] = psum[g] / fmaxf(pcnt[g], 1.0f) + bout[0];
}

extern "C" void kernel_launch(void* const* d_in, const int* in_sizes, int n_in,
                              void* d_out, int out_size, void* d_ws, size_t ws_size,
                              hipStream_t stream) {
    const float* x    = (const float*)d_in[0];   // [N,16]
    const int*   eidx = (const int*)d_in[1];     // [2,E]
    const float* ew   = (const float*)d_in[2];   // [E]
    const int*   batch= (const int*)d_in[3];     // [N]
    const float* W1   = (const float*)d_in[4];
    const float* b1   = (const float*)d_in[5];
    const float* W2   = (const float*)d_in[6];
    const float* b2   = (const float*)d_in[7];
    const float* W3   = (const float*)d_in[8];
    const float* b3   = (const float*)d_in[9];
    const float* Wout = (const float*)d_in[10];
    const float* bout = (const float*)d_in[11];
    float* out = (float*)d_out;

    const int N = in_sizes[0] / 16;  // 100000
    const int E = in_sizes[2];       // 3200000
    const int G = out_size;          // 64
    const int* src = eidx;
    const int* dst = eidx + E;

    size_t off = 0;
    auto carve = [&](size_t bytes) -> void* {
        void* p = (char*)d_ws + off;
        off += (bytes + 255) & ~(size_t)255;
        return p;
    };
    int*   cnt      = (int*)  carve((size_t)N * 4);
    float* psum     = (float*)carve(64 * 4);
    float* pcnt     = (float*)carve(64 * 4);
    size_t zero_bytes = off;                               // zeroed region
    int*   row_start= (int*)  carve((size_t)(N + 1) * 4);
    unsigned short* rnk = (unsigned short*)carve((size_t)E * 2);
    int2*  csr      = (int2*) carve((size_t)E * 8);
    float* dinv     = (float*)carve((size_t)N * 4);
    unsigned char* gA = (unsigned char*)carve((size_t)N * HID);
    unsigned char* gB = (unsigned char*)carve((size_t)N * HID);
    float* p        = (float*)carve((size_t)N * 4);   // pooling scalar
    (void)ws_size;

    hipMemsetAsync(d_ws, 0, zero_bytes, stream);

    const int nodeBlocks = (N + 3) / 4;
    const int edgeBlocks = (E + 255) / 256;
    const int waveBlocks = ((N + 63) / 64 * 64 + 255) / 256;

    // --- CSR build: one atomic pass + scan + atomic-free placement ---
    k_rank<<<edgeBlocks, 256, 0, stream>>>(dst, cnt, rnk, E);
    k_scan<<<1, 1024, 0, stream>>>(cnt, row_start, N);
    k_place<<<edgeBlocks, 256, 0, stream>>>(src, dst, ew, row_start, rnk, csr, E);
    k_degdinv<<<nodeBlocks, 256, 0, stream>>>(row_start, csr, dinv, N);

    // --- layer 1 matmul (prescaled fp8 g1) ---
    k_mm16<<<2048, 256, 0, stream>>>(x, W1, dinv, gA, N);
    // --- agg1 + sigmoid + @W2 (+dinv prescale) ---
    k_aggmm<1><<<nodeBlocks, 256, 0, stream>>>((const unsigned*)gA, b1, dinv,
                                               row_start, csr, W2, gB, N);
    // --- agg2 + sigmoid + @W3 (+dinv prescale) ---
    k_aggmm<1><<<nodeBlocks, 256, 0, stream>>>((const unsigned*)gB, b2, dinv,
                                               row_start, csr, W3, gA, N);
    // --- agg3 + dot(Wout) -> per-node scalar ---
    k_aggmm<2><<<nodeBlocks, 256, 0, stream>>>((const unsigned*)gA, b3, dinv,
                                               row_start, csr, Wout, p, N);

    // --- segmented mean-pool (sorted batch) + head ---
    k_poolseg<<<waveBlocks, 256, 0, stream>>>(p, batch, psum, pcnt, N);
    k_out<<<1, 64, 0, stream>>>(psum, pcnt, bout, out, G);
}

// Round 5
// 652.444 us; speedup vs baseline: 3.0141x; 1.1285x over previous
//
#include <hip/hip_runtime.h>
#include <hip/hip_bf16.h>

#define HID 64

typedef float v2f __attribute__((ext_vector_type(2)));

// HW fp8 (gfx950: OCP e4m3) conversions — self-consistent pack/unpack.
__device__ inline v2f fp8x2_lo(unsigned u) { return __builtin_amdgcn_cvt_pk_f32_fp8(u, false); }
__device__ inline v2f fp8x2_hi(unsigned u) { return __builtin_amdgcn_cvt_pk_f32_fp8(u, true); }
__device__ inline unsigned char f32_fp8(float a) {
    return (unsigned char)(__builtin_amdgcn_cvt_pk_fp8_f32(a, a, 0, false) & 0xff);
}

#define GSCALE 16.0f
#define GINV 0.0625f

// ---------------------------------------------------------------------------
// K1: rank pass — r[i] = old cnt[dst[i]]++  (the ONLY atomic pass over edges)
// ---------------------------------------------------------------------------
__global__ __launch_bounds__(256) void k_rank(const int* __restrict__ dst,
                                              int* __restrict__ cnt,
                                              unsigned short* __restrict__ rnk, int nE) {
    int i = blockIdx.x * blockDim.x + threadIdx.x;
    if (i < nE) rnk[i] = (unsigned short)atomicAdd(&cnt[dst[i]], 1);
}

// ---------------------------------------------------------------------------
// K2: single-block exclusive scan of cnt -> row_start[0..n]
// ---------------------------------------------------------------------------
__global__ __launch_bounds__(1024) void k_scan(const int* __restrict__ cnt,
                                               int* __restrict__ row_start, int n) {
    __shared__ int wsum[16];
    __shared__ int woff[16];
    __shared__ int carry_s;
    int tid = threadIdx.x;
    int lane = tid & 63, wv = tid >> 6;
    if (tid == 0) carry_s = 0;
    __syncthreads();
    const int CHUNK = 4096;
    for (int base = 0; base < n; base += CHUNK) {
        int idx0 = base + tid * 4;
        int v[4], local = 0;
#pragma unroll
        for (int j = 0; j < 4; ++j) {
            int i = idx0 + j;
            v[j] = (i < n) ? cnt[i] : 0;
            local += v[j];
        }
        int sc = local;
#pragma unroll
        for (int off = 1; off < 64; off <<= 1) {
            int t = __shfl_up(sc, off);
            if (lane >= off) sc += t;
        }
        if (lane == 63) wsum[wv] = sc;
        __syncthreads();
        if (tid == 0) {
            int acc = 0;
#pragma unroll
            for (int w = 0; w < 16; ++w) { woff[w] = acc; acc += wsum[w]; }
            wsum[0] = acc;
        }
        __syncthreads();
        int excl = carry_s + woff[wv] + sc - local;
#pragma unroll
        for (int j = 0; j < 4; ++j) {
            int i = idx0 + j;
            if (i < n) row_start[i] = excl;
            excl += v[j];
        }
        int total = wsum[0];
        __syncthreads();
        if (tid == 0) carry_s += total;
        __syncthreads();
    }
    if (tid == 0) row_start[n] = carry_s;
}

// ---------------------------------------------------------------------------
// K3: placement — pos = row_start[dst] + rank; csr[pos] = (src, raw ew).
// ---------------------------------------------------------------------------
__global__ __launch_bounds__(256) void k_place(const int* __restrict__ src,
                                               const int* __restrict__ dst,
                                               const float* __restrict__ ew,
                                               const int* __restrict__ row_start,
                                               const unsigned short* __restrict__ rnk,
                                               int2* __restrict__ csr, int nE) {
    int i = blockIdx.x * blockDim.x + threadIdx.x;
    if (i < nE) {
        int pos = row_start[dst[i]] + (int)rnk[i];
        int2 sw;
        sw.x = src[i];
        sw.y = __float_as_int(ew[i]);
        csr[pos] = sw;
    }
}

// ---------------------------------------------------------------------------
// K4: deg/dinv from CSR — wave per node, coalesced row sum, atomic-free.
// ---------------------------------------------------------------------------
__global__ __launch_bounds__(256) void k_degdinv(const int* __restrict__ row_start,
                                                 const int2* __restrict__ csr,
                                                 float* __restrict__ dinv,
                                                 int n_nodes) {
    int lane = threadIdx.x & 63;
    int wid = threadIdx.x >> 6;
    int node = blockIdx.x * 4 + wid;
    if (node >= n_nodes) return;
    int e0 = row_start[node], e1 = row_start[node + 1];
    float sum = 0.0f;
    for (int e = e0 + lane; e < e1; e += 64) sum += __int_as_float(csr[e].y);
#pragma unroll
    for (int off = 32; off; off >>= 1) sum += __shfl_xor(sum, off);
    if (lane == 0) dinv[node] = rsqrtf(fmaxf(sum + 1.0f, 1e-12f));
}

// ---------------------------------------------------------------------------
// K5: layer-1 matmul, fp8 prescaled output: g1[n][f] = fp8((x[n]@W1)[f]*dinv*16)
// ---------------------------------------------------------------------------
__global__ __launch_bounds__(256) void k_mm16(const float* __restrict__ in,
                                              const float* __restrict__ W,
                                              const float* __restrict__ dinv,
                                              unsigned char* __restrict__ out,
                                              int n_nodes) {
    __shared__ float Ws[16 * HID];
    for (int i = threadIdx.x; i < 16 * HID; i += blockDim.x) Ws[i] = W[i];
    __syncthreads();
    int lane = threadIdx.x & 63;
    int wid = threadIdx.x >> 6;
    int wavesTotal = gridDim.x * (blockDim.x >> 6);
    for (int node = blockIdx.x * (blockDim.x >> 6) + wid; node < n_nodes;
         node += wavesTotal) {
        float xr = (lane < 16) ? in[node * 16 + lane] : 0.0f;
        float acc = 0.0f;
#pragma unroll
        for (int k = 0; k < 16; ++k) {
            float xv = __shfl(xr, k);
            acc = fmaf(xv, Ws[k * HID + lane], acc);
        }
        out[node * HID + lane] = f32_fp8(acc * dinv[node] * GSCALE);
    }
}

// ---------------------------------------------------------------------------
// K6: fused aggregation — wave per node; quarter-wave per edge (fp8 row = one
//     64B line). Edge (s,w) pairs staged in wave-private LDS (ds_write_b64
//     once, quarter-broadcast ds_read_b64 per 4-edge group) — no shfl in the
//     main loop. float2 accumulators -> v_pk_fma_f32.
//     a_f = b[f] + dinv[d]/16*(g[d][f] + sum_e ew_e * g[src_e][f])
//     EPI==1 epilogue: o = sigmoid(a) @ Wn, stored fp8(o*dinv*16).
//       Matvec: step s: lane i reads Ws bytes [1024 s + 16 i] (ds_read_b128,
//       conflict-free contiguous), act[4s+q] via ONE bpermute of per-lane
//       sel = sig_{lane>>4} from lane (lane&48)+s. Quarter-fold at the end.
//     EPI==2 epilogue: out[d] = dot(a, Wn)  [pool scalar]
// ---------------------------------------------------------------------------
template <int EPI>
__global__ __launch_bounds__(256) void k_aggmm(const unsigned int* __restrict__ g32,
                                               const float* __restrict__ bias,
                                               const float* __restrict__ dinv,
                                               const int* __restrict__ row_start,
                                               const int2* __restrict__ csr,
                                               const float* __restrict__ Wn,
                                               void* __restrict__ outv,
                                               int n_nodes) {
    __shared__ float Ws[(EPI == 1) ? HID * HID : 64];
    __shared__ int2 esc[4][64];  // per-wave edge scratch
    if (EPI == 1) {
        for (int i = threadIdx.x; i < HID * HID; i += blockDim.x) Ws[i] = Wn[i];
        __syncthreads();
    }
    int lane = threadIdx.x & 63;
    int wid = threadIdx.x >> 6;
    int node = blockIdx.x * 4 + wid;
    if (node >= n_nodes) return;
    int p = lane & 15;   // dword within fp8 row (features 4p..4p+3)
    int q = lane >> 4;   // quarter = edge slot within a group of 4

    v2f acc01 = {0.0f, 0.0f}, acc23 = {0.0f, 0.0f};
    {   // self term (weight 1), quarter 0 only
        unsigned su = g32[node * 16 + p];
        if (q == 0) { acc01 = fp8x2_lo(su); acc23 = fp8x2_hi(su); }
    }
    int e0 = row_start[node], e1 = row_start[node + 1];
    for (int base = e0; base < e1; base += 64) {
        int m = min(64, e1 - base);
        int2 sw = {0, 0};
        if (lane < m) sw = csr[base + lane];
        esc[wid][lane] = sw;
        int ng = (m + 3) >> 2;  // groups of 4 edges
        int j = 0;
        for (; j + 4 <= ng; j += 4) {  // 16 edges, 4 gathers in flight
            int2 eA = esc[wid][4 * j + q];
            int2 eB = esc[wid][4 * j + 4 + q];
            int2 eC = esc[wid][4 * j + 8 + q];
            int2 eD = esc[wid][4 * j + 12 + q];
            unsigned uA = g32[(unsigned)eA.x * 16u + p];
            unsigned uB = g32[(unsigned)eB.x * 16u + p];
            unsigned uC = g32[(unsigned)eC.x * 16u + p];
            unsigned uD = g32[(unsigned)eD.x * 16u + p];
            float wA = __int_as_float(eA.y);
            float wB = __int_as_float(eB.y);
            float wC = __int_as_float(eC.y);
            float wD = __int_as_float(eD.y);
            acc01 += fp8x2_lo(uA) * wA; acc23 += fp8x2_hi(uA) * wA;
            acc01 += fp8x2_lo(uB) * wB; acc23 += fp8x2_hi(uB) * wB;
            acc01 += fp8x2_lo(uC) * wC; acc23 += fp8x2_hi(uC) * wC;
            acc01 += fp8x2_lo(uD) * wD; acc23 += fp8x2_hi(uD) * wD;
        }
        for (; j < ng; ++j) {
            int2 eA = esc[wid][4 * j + q];
            unsigned uA = g32[(unsigned)eA.x * 16u + p];
            float wA = __int_as_float(eA.y);
            acc01 += fp8x2_lo(uA) * wA;
            acc23 += fp8x2_hi(uA) * wA;
        }
    }
    // fold quarters: all lanes end with full sums for features 4p..4p+3
    float a0 = acc01.x, a1 = acc01.y, a2 = acc23.x, a3 = acc23.y;
    a0 += __shfl_xor(a0, 16); a0 += __shfl_xor(a0, 32);
    a1 += __shfl_xor(a1, 16); a1 += __shfl_xor(a1, 32);
    a2 += __shfl_xor(a2, 16); a2 += __shfl_xor(a2, 32);
    a3 += __shfl_xor(a3, 16); a3 += __shfl_xor(a3, 32);

    float diRaw = dinv[node];
    float di = diRaw * GINV;  // undo GSCALE on the gathered table
    float4 bv = ((const float4*)bias)[p];
    a0 = fmaf(di, a0, bv.x);
    a1 = fmaf(di, a1, bv.y);
    a2 = fmaf(di, a2, bv.z);
    a3 = fmaf(di, a3, bv.w);

    if (EPI == 1) {
        float s0 = 1.0f / (1.0f + __expf(-a0));
        float s1 = 1.0f / (1.0f + __expf(-a1));
        float s2 = 1.0f / (1.0f + __expf(-a2));
        float s3 = 1.0f / (1.0f + __expf(-a3));
        // per-lane sel: lane l carries sig[4*(l&15) + (l>>4)]
        float sel = (q == 0) ? s0 : (q == 1) ? s1 : (q == 2) ? s2 : s3;
        int selbase = lane & 48;  // 16*q
        v2f o01 = {0.0f, 0.0f}, o23 = {0.0f, 0.0f};
#pragma unroll
        for (int st = 0; st < 16; ++st) {
            float av = __shfl(sel, selbase + st);           // act[4*st + q]
            float4 wv = ((const float4*)Ws)[(4 * st + q) * 16 + p];
            v2f wlo = {wv.x, wv.y}, whi = {wv.z, wv.w};
            o01 += wlo * av;
            o23 += whi * av;
        }
        float o0 = o01.x, o1 = o01.y, o2 = o23.x, o3 = o23.y;
        o0 += __shfl_xor(o0, 16); o0 += __shfl_xor(o0, 32);
        o1 += __shfl_xor(o1, 16); o1 += __shfl_xor(o1, 32);
        o2 += __shfl_xor(o2, 16); o2 += __shfl_xor(o2, 32);
        o3 += __shfl_xor(o3, 16); o3 += __shfl_xor(o3, 32);
        if (lane < 16) {
            float sc = diRaw * GSCALE;
            unsigned pk = __builtin_amdgcn_cvt_pk_fp8_f32(o0 * sc, o1 * sc, 0, false);
            pk = __builtin_amdgcn_cvt_pk_fp8_f32(o2 * sc, o3 * sc, pk, true);
            ((unsigned*)outv)[node * 16 + p] = pk;
        }
    } else {
        float4 wv = ((const float4*)Wn)[p];
        float v = a0 * wv.x + a1 * wv.y + a2 * wv.z + a3 * wv.w;
        v += __shfl_xor(v, 1);
        v += __shfl_xor(v, 2);
        v += __shfl_xor(v, 4);
        v += __shfl_xor(v, 8);
        if (lane == 0) ((float*)outv)[node] = v;
    }
}

// ---------------------------------------------------------------------------
// K7: segmented pool over sorted batch — one atomic per uniform 64-node wave
// ---------------------------------------------------------------------------
__global__ __launch_bounds__(256) void k_poolseg(const float* __restrict__ p,
                                                 const int* __restrict__ batch,
                                                 float* __restrict__ psum,
                                                 float* __restrict__ pcnt,
                                                 int n_nodes) {
    int lane = threadIdx.x & 63;
    int gw = (blockIdx.x * blockDim.x + threadIdx.x) >> 6;
    int node = gw * 64 + lane;
    bool valid = node < n_nodes;
    float v = valid ? p[node] : 0.0f;
    int g = valid ? batch[node] : -1;
    int g0 = __shfl(g, 0);
    if (__all((g == g0) && valid)) {
#pragma unroll
        for (int off = 32; off; off >>= 1) v += __shfl_xor(v, off);
        if (lane == 0) {
            atomicAdd(&psum[g0], v);
            atomicAdd(&pcnt[g0], 64.0f);
        }
    } else if (valid) {
        atomicAdd(&psum[g], v);
        atomicAdd(&pcnt[g], 1.0f);
    }
}

// K8: final — out[g] = psum[g]/max(pcnt[g],1) + bout
__global__ __launch_bounds__(64) void k_out(const float* __restrict__ psum,
                                            const float* __restrict__ pcnt,
                                            const float* __restrict__ bout,
                                            float* __restrict__ out, int G) {
    int g = threadIdx.x;
    if (g < G) out[g] = psum[g] / fmaxf(pcnt[g], 1.0f) + bout[0];
}

extern "C" void kernel_launch(void* const* d_in, const int* in_sizes, int n_in,
                              void* d_out, int out_size, void* d_ws, size_t ws_size,
                              hipStream_t stream) {
    const float* x    = (const float*)d_in[0];   // [N,16]
    const int*   eidx = (const int*)d_in[1];     // [2,E]
    const float* ew   = (const float*)d_in[2];   // [E]
    const int*   batch= (const int*)d_in[3];     // [N]
    const float* W1   = (const float*)d_in[4];
    const float* b1   = (const float*)d_in[5];
    const float* W2   = (const float*)d_in[6];
    const float* b2   = (const float*)d_in[7];
    const float* W3   = (const float*)d_in[8];
    const float* b3   = (const float*)d_in[9];
    const float* Wout = (const float*)d_in[10];
    const float* bout = (const float*)d_in[11];
    float* out = (float*)d_out;

    const int N = in_sizes[0] / 16;  // 100000
    const int E = in_sizes[2];       // 3200000
    const int G = out_size;          // 64
    const int* src = eidx;
    const int* dst = eidx + E;

    size_t off = 0;
    auto carve = [&](size_t bytes) -> void* {
        void* p = (char*)d_ws + off;
        off += (bytes + 255) & ~(size_t)255;
        return p;
    };
    int*   cnt      = (int*)  carve((size_t)N * 4);
    float* psum     = (float*)carve(64 * 4);
    float* pcnt     = (float*)carve(64 * 4);
    size_t zero_bytes = off;                               // zeroed region
    int*   row_start= (int*)  carve((size_t)(N + 1) * 4);
    unsigned short* rnk = (unsigned short*)carve((size_t)E * 2);
    int2*  csr      = (int2*) carve((size_t)E * 8);
    float* dinv     = (float*)carve((size_t)N * 4);
    unsigned char* gA = (unsigned char*)carve((size_t)N * HID);
    unsigned char* gB = (unsigned char*)carve((size_t)N * HID);
    float* p        = (float*)carve((size_t)N * 4);   // pooling scalar
    (void)ws_size;

    hipMemsetAsync(d_ws, 0, zero_bytes, stream);

    const int nodeBlocks = (N + 3) / 4;
    const int edgeBlocks = (E + 255) / 256;
    const int waveBlocks = ((N + 63) / 64 * 64 + 255) / 256;

    // --- CSR build: one atomic pass + scan + atomic-free placement ---
    k_rank<<<edgeBlocks, 256, 0, stream>>>(dst, cnt, rnk, E);
    k_scan<<<1, 1024, 0, stream>>>(cnt, row_start, N);
    k_place<<<edgeBlocks, 256, 0, stream>>>(src, dst, ew, row_start, rnk, csr, E);
    k_degdinv<<<nodeBlocks, 256, 0, stream>>>(row_start, csr, dinv, N);

    // --- layer 1 matmul (prescaled fp8 g1) ---
    k_mm16<<<2048, 256, 0, stream>>>(x, W1, dinv, gA, N);
    // --- agg1 + sigmoid + @W2 (+dinv prescale) ---
    k_aggmm<1><<<nodeBlocks, 256, 0, stream>>>((const unsigned*)gA, b1, dinv,
                                               row_start, csr, W2, gB, N);
    // --- agg2 + sigmoid + @W3 (+dinv prescale) ---
    k_aggmm<1><<<nodeBlocks, 256, 0, stream>>>((const unsigned*)gB, b2, dinv,
                                               row_start, csr, W3, gA, N);
    // --- agg3 + dot(Wout) -> per-node scalar ---
    k_aggmm<2><<<nodeBlocks, 256, 0, stream>>>((const unsigned*)gA, b3, dinv,
                                               row_start, csr, Wout, p, N);

    // --- segmented mean-pool (sorted batch) + head ---
    k_poolseg<<<waveBlocks, 256, 0, stream>>>(p, batch, psum, pcnt, N);
    k_out<<<1, 64, 0, stream>>>(psum, pcnt, bout, out, G);
}

// Round 6
// 512.026 us; speedup vs baseline: 3.8407x; 1.2742x over previous
//
#include <hip/hip_runtime.h>
#include <hip/hip_bf16.h>

#define HID 64
#define P_BLOCKS 256   // pass-1 partition blocks
#define MAXB 512       // max coarse buckets (N <= 131072)

typedef float v2f __attribute__((ext_vector_type(2)));

// HW fp8 (gfx950: OCP e4m3) conversions — self-consistent pack/unpack.
__device__ inline v2f fp8x2_lo(unsigned u) { return __builtin_amdgcn_cvt_pk_f32_fp8(u, false); }
__device__ inline v2f fp8x2_hi(unsigned u) { return __builtin_amdgcn_cvt_pk_f32_fp8(u, true); }
__device__ inline unsigned char f32_fp8(float a) {
    return (unsigned char)(__builtin_amdgcn_cvt_pk_fp8_f32(a, a, 0, false) & 0xff);
}

#define GSCALE 16.0f
#define GINV 0.0625f

// ---------------------------------------------------------------------------
// P1a: per-block LDS histogram of coarse bucket (dst>>8) over this block's
//      contiguous edge chunk. No global atomics.
// ---------------------------------------------------------------------------
__global__ __launch_bounds__(256) void kp1a_hist(const int* __restrict__ dst,
                                                 int* __restrict__ ghist,
                                                 int nE, int B, int chunk) {
    __shared__ int h[MAXB];
    for (int b = threadIdx.x; b < B; b += 256) h[b] = 0;
    __syncthreads();
    int lo = blockIdx.x * chunk;
    int hi = min(nE, lo + chunk);
    for (int i = lo + threadIdx.x; i < hi; i += 256)
        atomicAdd(&h[dst[i] >> 8], 1);
    __syncthreads();
    for (int b = threadIdx.x; b < B; b += 256)
        ghist[blockIdx.x * B + b] = h[b];
}

// ---------------------------------------------------------------------------
// P1b: single-block scan. tot[b] = sum_p ghist[p][b]; exclusive scan over b
//      -> bstart[b]; per-(p,b) running offsets -> goff[p][b].
// ---------------------------------------------------------------------------
__global__ __launch_bounds__(512) void kp1b_scan(const int* __restrict__ ghist,
                                                 int* __restrict__ goff,
                                                 int* __restrict__ bstart,
                                                 int B, int nE) {
    __shared__ int wsum[8];
    __shared__ int woff[8];
    int tid = threadIdx.x;
    int lane = tid & 63, wv = tid >> 6;
    int b = tid;
    int tot = 0;
    if (b < B)
        for (int p = 0; p < P_BLOCKS; ++p) tot += ghist[p * B + b];
    // exclusive scan of tot over 512 threads
    int sc = tot;
#pragma unroll
    for (int off = 1; off < 64; off <<= 1) {
        int t = __shfl_up(sc, off);
        if (lane >= off) sc += t;
    }
    if (lane == 63) wsum[wv] = sc;
    __syncthreads();
    if (tid == 0) {
        int acc = 0;
#pragma unroll
        for (int w = 0; w < 8; ++w) { woff[w] = acc; acc += wsum[w]; }
        bstart[B] = acc;  // == nE
    }
    __syncthreads();
    int excl = woff[wv] + sc - tot;
    if (b < B) {
        bstart[b] = excl;
        int run = excl;
        for (int p = 0; p < P_BLOCKS; ++p) {
            goff[p * B + b] = run;
            run += ghist[p * B + b];
        }
    }
}

// ---------------------------------------------------------------------------
// P1c: partition scatter. pos from LDS cursors (init goff[block][*]).
//      bsw[pos] = (src | dstlo<<20, ew_bits). Per-block per-bucket writes are
//      sequential -> L2 write-combines into full lines. No global atomics.
// ---------------------------------------------------------------------------
__global__ __launch_bounds__(256) void kp1c_scatter(const int* __restrict__ src,
                                                    const int* __restrict__ dst,
                                                    const float* __restrict__ ew,
                                                    const int* __restrict__ goff,
                                                    int2* __restrict__ bsw,
                                                    int nE, int B, int chunk) {
    __shared__ int cur[MAXB];
    for (int b = threadIdx.x; b < B; b += 256)
        cur[b] = goff[blockIdx.x * B + b];
    __syncthreads();
    int lo = blockIdx.x * chunk;
    int hi = min(nE, lo + chunk);
    for (int i = lo + threadIdx.x; i < hi; i += 256) {
        int d = dst[i];
        int pos = atomicAdd(&cur[d >> 8], 1);
        int2 v;
        v.x = src[i] | ((d & 255) << 20);
        v.y = __float_as_int(ew[i]);
        bsw[pos] = v;
    }
}

// ---------------------------------------------------------------------------
// P2: per-bucket CSR build — one block per bucket (256 nodes). LDS histogram
//     of dstlo (+ LDS float atomic deg accumulation), LDS scan -> row_start,
//     dinv; then place into csr within the bucket's contiguous region.
// ---------------------------------------------------------------------------
__global__ __launch_bounds__(256) void kp2_build(const int2* __restrict__ bsw,
                                                 const int* __restrict__ bstart,
                                                 int* __restrict__ row_start,
                                                 float* __restrict__ dinv,
                                                 int2* __restrict__ csr,
                                                 int n_nodes) {
    __shared__ int cnt[256];
    __shared__ float degw[256];
    __shared__ int excl[256];
    __shared__ int cur[256];
    __shared__ int wsum[4];
    __shared__ int woff[4];
    int tid = threadIdx.x;
    int lane = tid & 63, wv = tid >> 6;
    int b = blockIdx.x;
    int e0 = bstart[b], e1 = bstart[b + 1];
    cnt[tid] = 0;
    degw[tid] = 0.0f;
    __syncthreads();
    for (int e = e0 + tid; e < e1; e += 256) {
        int2 v = bsw[e];
        int dlo = (v.x >> 20) & 255;
        atomicAdd(&cnt[dlo], 1);
        atomicAdd(&degw[dlo], __int_as_float(v.y));
    }
    __syncthreads();
    // exclusive scan of cnt[256]
    int c = cnt[tid];
    int sc = c;
#pragma unroll
    for (int off = 1; off < 64; off <<= 1) {
        int t = __shfl_up(sc, off);
        if (lane >= off) sc += t;
    }
    if (lane == 63) wsum[wv] = sc;
    __syncthreads();
    if (tid == 0) {
        int acc = 0;
#pragma unroll
        for (int w = 0; w < 4; ++w) { woff[w] = acc; acc += wsum[w]; }
    }
    __syncthreads();
    int ex = woff[wv] + sc - c;
    excl[tid] = ex;
    cur[tid] = ex;
    int node = (b << 8) + tid;
    if (node < n_nodes) {
        row_start[node] = e0 + ex;
        dinv[node] = rsqrtf(fmaxf(degw[tid] + 1.0f, 1e-12f));
    } else if (node == n_nodes) {
        row_start[node] = e0 + ex;  // == total edge count boundary
    }
    if (b == 0 && tid == 0) row_start[n_nodes] = bstart[gridDim.x];  // safety: == E
    __syncthreads();
    for (int e = e0 + tid; e < e1; e += 256) {
        int2 v = bsw[e];
        int dlo = (v.x >> 20) & 255;
        int pos = atomicAdd(&cur[dlo], 1);
        int2 o;
        o.x = v.x & 0xFFFFF;
        o.y = v.y;
        csr[e0 + pos] = o;
    }
}

// ---------------------------------------------------------------------------
// K5: layer-1 matmul, fp8 prescaled output: g1[n][f] = fp8((x[n]@W1)[f]*dinv*16)
// ---------------------------------------------------------------------------
__global__ __launch_bounds__(256) void k_mm16(const float* __restrict__ in,
                                              const float* __restrict__ W,
                                              const float* __restrict__ dinv,
                                              unsigned char* __restrict__ out,
                                              int n_nodes) {
    __shared__ float Ws[16 * HID];
    for (int i = threadIdx.x; i < 16 * HID; i += blockDim.x) Ws[i] = W[i];
    __syncthreads();
    int lane = threadIdx.x & 63;
    int wid = threadIdx.x >> 6;
    int wavesTotal = gridDim.x * (blockDim.x >> 6);
    for (int node = blockIdx.x * (blockDim.x >> 6) + wid; node < n_nodes;
         node += wavesTotal) {
        float xr = (lane < 16) ? in[node * 16 + lane] : 0.0f;
        float acc = 0.0f;
#pragma unroll
        for (int k = 0; k < 16; ++k) {
            float xv = __shfl(xr, k);
            acc = fmaf(xv, Ws[k * HID + lane], acc);
        }
        out[node * HID + lane] = f32_fp8(acc * dinv[node] * GSCALE);
    }
}

// ---------------------------------------------------------------------------
// K6: fused aggregation — wave per node; quarter-wave per edge (fp8 row = one
//     64B line). Edge (s,w) pairs staged in wave-private LDS; float2
//     accumulators -> v_pk_fma_f32.  (unchanged from R5)
// ---------------------------------------------------------------------------
template <int EPI>
__global__ __launch_bounds__(256) void k_aggmm(const unsigned int* __restrict__ g32,
                                               const float* __restrict__ bias,
                                               const float* __restrict__ dinv,
                                               const int* __restrict__ row_start,
                                               const int2* __restrict__ csr,
                                               const float* __restrict__ Wn,
                                               void* __restrict__ outv,
                                               int n_nodes) {
    __shared__ float Ws[(EPI == 1) ? HID * HID : 64];
    __shared__ int2 esc[4][64];  // per-wave edge scratch
    if (EPI == 1) {
        for (int i = threadIdx.x; i < HID * HID; i += blockDim.x) Ws[i] = Wn[i];
        __syncthreads();
    }
    int lane = threadIdx.x & 63;
    int wid = threadIdx.x >> 6;
    int node = blockIdx.x * 4 + wid;
    if (node >= n_nodes) return;
    int p = lane & 15;   // dword within fp8 row (features 4p..4p+3)
    int q = lane >> 4;   // quarter = edge slot within a group of 4

    v2f acc01 = {0.0f, 0.0f}, acc23 = {0.0f, 0.0f};
    {   // self term (weight 1), quarter 0 only
        unsigned su = g32[node * 16 + p];
        if (q == 0) { acc01 = fp8x2_lo(su); acc23 = fp8x2_hi(su); }
    }
    int e0 = row_start[node], e1 = row_start[node + 1];
    for (int base = e0; base < e1; base += 64) {
        int m = min(64, e1 - base);
        int2 sw = {0, 0};
        if (lane < m) sw = csr[base + lane];
        esc[wid][lane] = sw;
        int ng = (m + 3) >> 2;  // groups of 4 edges
        int j = 0;
        for (; j + 4 <= ng; j += 4) {  // 16 edges, 4 gathers in flight
            int2 eA = esc[wid][4 * j + q];
            int2 eB = esc[wid][4 * j + 4 + q];
            int2 eC = esc[wid][4 * j + 8 + q];
            int2 eD = esc[wid][4 * j + 12 + q];
            unsigned uA = g32[(unsigned)eA.x * 16u + p];
            unsigned uB = g32[(unsigned)eB.x * 16u + p];
            unsigned uC = g32[(unsigned)eC.x * 16u + p];
            unsigned uD = g32[(unsigned)eD.x * 16u + p];
            float wA = __int_as_float(eA.y);
            float wB = __int_as_float(eB.y);
            float wC = __int_as_float(eC.y);
            float wD = __int_as_float(eD.y);
            acc01 += fp8x2_lo(uA) * wA; acc23 += fp8x2_hi(uA) * wA;
            acc01 += fp8x2_lo(uB) * wB; acc23 += fp8x2_hi(uB) * wB;
            acc01 += fp8x2_lo(uC) * wC; acc23 += fp8x2_hi(uC) * wC;
            acc01 += fp8x2_lo(uD) * wD; acc23 += fp8x2_hi(uD) * wD;
        }
        for (; j < ng; ++j) {
            int2 eA = esc[wid][4 * j + q];
            unsigned uA = g32[(unsigned)eA.x * 16u + p];
            float wA = __int_as_float(eA.y);
            acc01 += fp8x2_lo(uA) * wA;
            acc23 += fp8x2_hi(uA) * wA;
        }
    }
    // fold quarters: all lanes end with full sums for features 4p..4p+3
    float a0 = acc01.x, a1 = acc01.y, a2 = acc23.x, a3 = acc23.y;
    a0 += __shfl_xor(a0, 16); a0 += __shfl_xor(a0, 32);
    a1 += __shfl_xor(a1, 16); a1 += __shfl_xor(a1, 32);
    a2 += __shfl_xor(a2, 16); a2 += __shfl_xor(a2, 32);
    a3 += __shfl_xor(a3, 16); a3 += __shfl_xor(a3, 32);

    float diRaw = dinv[node];
    float di = diRaw * GINV;  // undo GSCALE on the gathered table
    float4 bv = ((const float4*)bias)[p];
    a0 = fmaf(di, a0, bv.x);
    a1 = fmaf(di, a1, bv.y);
    a2 = fmaf(di, a2, bv.z);
    a3 = fmaf(di, a3, bv.w);

    if (EPI == 1) {
        float s0 = 1.0f / (1.0f + __expf(-a0));
        float s1 = 1.0f / (1.0f + __expf(-a1));
        float s2 = 1.0f / (1.0f + __expf(-a2));
        float s3 = 1.0f / (1.0f + __expf(-a3));
        // per-lane sel: lane l carries sig[4*(l&15) + (l>>4)]
        float sel = (q == 0) ? s0 : (q == 1) ? s1 : (q == 2) ? s2 : s3;
        int selbase = lane & 48;  // 16*q
        v2f o01 = {0.0f, 0.0f}, o23 = {0.0f, 0.0f};
#pragma unroll
        for (int st = 0; st < 16; ++st) {
            float av = __shfl(sel, selbase + st);           // act[4*st + q]
            float4 wv = ((const float4*)Ws)[(4 * st + q) * 16 + p];
            v2f wlo = {wv.x, wv.y}, whi = {wv.z, wv.w};
            o01 += wlo * av;
            o23 += whi * av;
        }
        float o0 = o01.x, o1 = o01.y, o2 = o23.x, o3 = o23.y;
        o0 += __shfl_xor(o0, 16); o0 += __shfl_xor(o0, 32);
        o1 += __shfl_xor(o1, 16); o1 += __shfl_xor(o1, 32);
        o2 += __shfl_xor(o2, 16); o2 += __shfl_xor(o2, 32);
        o3 += __shfl_xor(o3, 16); o3 += __shfl_xor(o3, 32);
        if (lane < 16) {
            float sc = diRaw * GSCALE;
            unsigned pk = __builtin_amdgcn_cvt_pk_fp8_f32(o0 * sc, o1 * sc, 0, false);
            pk = __builtin_amdgcn_cvt_pk_fp8_f32(o2 * sc, o3 * sc, pk, true);
            ((unsigned*)outv)[node * 16 + p] = pk;
        }
    } else {
        float4 wv = ((const float4*)Wn)[p];
        float v = a0 * wv.x + a1 * wv.y + a2 * wv.z + a3 * wv.w;
        v += __shfl_xor(v, 1);
        v += __shfl_xor(v, 2);
        v += __shfl_xor(v, 4);
        v += __shfl_xor(v, 8);
        if (lane == 0) ((float*)outv)[node] = v;
    }
}

// ---------------------------------------------------------------------------
// K7: segmented pool over sorted batch — one atomic per uniform 64-node wave
// ---------------------------------------------------------------------------
__global__ __launch_bounds__(256) void k_poolseg(const float* __restrict__ p,
                                                 const int* __restrict__ batch,
                                                 float* __restrict__ psum,
                                                 float* __restrict__ pcnt,
                                                 int n_nodes) {
    int lane = threadIdx.x & 63;
    int gw = (blockIdx.x * blockDim.x + threadIdx.x) >> 6;
    int node = gw * 64 + lane;
    bool valid = node < n_nodes;
    float v = valid ? p[node] : 0.0f;
    int g = valid ? batch[node] : -1;
    int g0 = __shfl(g, 0);
    if (__all((g == g0) && valid)) {
#pragma unroll
        for (int off = 32; off; off >>= 1) v += __shfl_xor(v, off);
        if (lane == 0) {
            atomicAdd(&psum[g0], v);
            atomicAdd(&pcnt[g0], 64.0f);
        }
    } else if (valid) {
        atomicAdd(&psum[g], v);
        atomicAdd(&pcnt[g], 1.0f);
    }
}

// K8: final — out[g] = psum[g]/max(pcnt[g],1) + bout
__global__ __launch_bounds__(64) void k_out(const float* __restrict__ psum,
                                            const float* __restrict__ pcnt,
                                            const float* __restrict__ bout,
                                            float* __restrict__ out, int G) {
    int g = threadIdx.x;
    if (g < G) out[g] = psum[g] / fmaxf(pcnt[g], 1.0f) + bout[0];
}

extern "C" void kernel_launch(void* const* d_in, const int* in_sizes, int n_in,
                              void* d_out, int out_size, void* d_ws, size_t ws_size,
                              hipStream_t stream) {
    const float* x    = (const float*)d_in[0];   // [N,16]
    const int*   eidx = (const int*)d_in[1];     // [2,E]
    const float* ew   = (const float*)d_in[2];   // [E]
    const int*   batch= (const int*)d_in[3];     // [N]
    const float* W1   = (const float*)d_in[4];
    const float* b1   = (const float*)d_in[5];
    const float* W2   = (const float*)d_in[6];
    const float* b2   = (const float*)d_in[7];
    const float* W3   = (const float*)d_in[8];
    const float* b3   = (const float*)d_in[9];
    const float* Wout = (const float*)d_in[10];
    const float* bout = (const float*)d_in[11];
    float* out = (float*)d_out;

    const int N = in_sizes[0] / 16;  // 100000
    const int E = in_sizes[2];       // 3200000
    const int G = out_size;          // 64
    const int* src = eidx;
    const int* dst = eidx + E;
    const int B = (N + 255) >> 8;                // coarse buckets (391)
    const int chunk = (E + P_BLOCKS - 1) / P_BLOCKS;

    size_t off = 0;
    auto carve = [&](size_t bytes) -> void* {
        void* p = (char*)d_ws + off;
        off += (bytes + 255) & ~(size_t)255;
        return p;
    };
    float* psum     = (float*)carve(64 * 4);
    float* pcnt     = (float*)carve(64 * 4);
    size_t zero_bytes = off;                               // only psum/pcnt
    int*   ghist    = (int*)  carve((size_t)P_BLOCKS * B * 4);
    int*   goff     = (int*)  carve((size_t)P_BLOCKS * B * 4);
    int*   bstart   = (int*)  carve((size_t)(B + 1) * 4);
    int2*  bsw      = (int2*) carve((size_t)E * 8);
    int*   row_start= (int*)  carve((size_t)(N + 1) * 4);
    int2*  csr      = (int2*) carve((size_t)E * 8);
    float* dinv     = (float*)carve((size_t)N * 4);
    unsigned char* gA = (unsigned char*)carve((size_t)N * HID);
    unsigned char* gB = (unsigned char*)carve((size_t)N * HID);
    float* p        = (float*)carve((size_t)N * 4);   // pooling scalar
    (void)ws_size;

    hipMemsetAsync(d_ws, 0, zero_bytes, stream);

    const int nodeBlocks = (N + 3) / 4;
    const int waveBlocks = ((N + 63) / 64 * 64 + 255) / 256;

    // --- CSR build: radix partition, zero global atomics ---
    kp1a_hist<<<P_BLOCKS, 256, 0, stream>>>(dst, ghist, E, B, chunk);
    kp1b_scan<<<1, 512, 0, stream>>>(ghist, goff, bstart, B, E);
    kp1c_scatter<<<P_BLOCKS, 256, 0, stream>>>(src, dst, ew, goff, bsw, E, B, chunk);
    kp2_build<<<B, 256, 0, stream>>>(bsw, bstart, row_start, dinv, csr, N);

    // --- layer 1 matmul (prescaled fp8 g1) ---
    k_mm16<<<2048, 256, 0, stream>>>(x, W1, dinv, gA, N);
    // --- agg1 + sigmoid + @W2 (+dinv prescale) ---
    k_aggmm<1><<<nodeBlocks, 256, 0, stream>>>((const unsigned*)gA, b1, dinv,
                                               row_start, csr, W2, gB, N);
    // --- agg2 + sigmoid + @W3 (+dinv prescale) ---
    k_aggmm<1><<<nodeBlocks, 256, 0, stream>>>((const unsigned*)gB, b2, dinv,
                                               row_start, csr, W3, gA, N);
    // --- agg3 + dot(Wout) -> per-node scalar ---
    k_aggmm<2><<<nodeBlocks, 256, 0, stream>>>((const unsigned*)gA, b3, dinv,
                                               row_start, csr, Wout, p, N);

    // --- segmented mean-pool (sorted batch) + head ---
    k_poolseg<<<waveBlocks, 256, 0, stream>>>(p, batch, psum, pcnt, N);
    k_out<<<1, 64, 0, stream>>>(psum, pcnt, bout, out, G);
}